// Round 1
// baseline (10899.916 us; speedup 1.0000x reference)
//
#include <hip/hip_runtime.h>
#include <hip/hip_bf16.h>

// ---------------------------------------------------------------------------
// CompositePulseTransformerDecoder — MI355X (gfx950)
// Strategy: KV-cached incremental decode + cross-attn collapsed to constant.
// 8 blocks x 512 threads; each block owns 16 batch rows end-to-end (no
// inter-block sync needed: batch rows are independent chains).
// bf16 MFMA 16x16x32 for all GEMMs; f32 LN/softmax; bf16 KV cache in ws.
// ---------------------------------------------------------------------------

typedef __attribute__((ext_vector_type(8))) short short8;
typedef __attribute__((ext_vector_type(4))) float f32x4;

#define EPS_ 1e-5f
#define LDW 264     // padded f32/bf16 row stride for 256-wide LDS tiles
#define LDH 1032    // padded stride for 1024-wide hidden tile

__device__ __forceinline__ unsigned short f2b(float x){
  union { float f; unsigned u; } c; c.f = x;
  unsigned r = (c.u + 0x7fffu + ((c.u >> 16) & 1u)) >> 16;
  return (unsigned short)r;
}
__device__ __forceinline__ float b2f(unsigned short u){
  union { unsigned u; float f; } c; c.u = ((unsigned)u) << 16;
  return c.f;
}

// ws layout (bytes)
#define OFF_WQKV 0ull            // 12*768*256  bf16 = 4718592 B
#define OFF_WO   4718592ull      // 12*256*256  bf16 = 1572864 B
#define OFF_L1   6291456ull      // 12*1024*256 bf16 = 6291456 B
#define OFF_L2   12582912ull     // 12*256*1024 bf16 = 6291456 B
#define OFF_SRC  18874368ull     // 128*256 f32 = 131072 B
#define OFF_CC   19005440ull     // 12*128*256 f32 = 1572864 B
#define OFF_CACHE 20578304ull    // 128*12*16*512 bf16 = 25165824 B
// total 45744128 B (~43.6 MB)

// ---------------- weight f32 -> bf16 conversion --------------------------
__global__ void k_conv(const float* __restrict__ wqkv, const float* __restrict__ wo,
                       const float* __restrict__ l1, const float* __restrict__ l2,
                       unsigned short* __restrict__ dst){
  const long long n0 = 12LL*768*256;
  const long long n1 = n0 + 12LL*256*256;
  const long long n2 = n1 + 12LL*1024*256;
  const long long n3 = n2 + 12LL*256*1024;
  for (long long idx = (long long)blockIdx.x*256 + threadIdx.x; idx < n3;
       idx += (long long)gridDim.x*256){
    float v;
    if (idx < n0) v = wqkv[idx];
    else if (idx < n1) v = wo[idx - n0];
    else if (idx < n2) v = l1[idx - n1];
    else v = l2[idx - n2];
    dst[idx] = f2b(v);
  }
}

// ---------------- src = vec @ tok_W.T + tok_b ----------------------------
__global__ void k_src(const float* __restrict__ U_real, const float* __restrict__ U_imag,
                      const float* __restrict__ tok_W, const float* __restrict__ tok_b,
                      float* __restrict__ src){
  int b = blockIdx.x, n = threadIdx.x;
  const float* w = tok_W + n*128;
  const float* ur = U_real + b*64;
  const float* ui = U_imag + b*64;
  float acc = tok_b[n];
  #pragma unroll 8
  for (int k = 0; k < 64; ++k) acc += w[k]*ur[k];
  #pragma unroll 8
  for (int k = 0; k < 64; ++k) acc += w[64+k]*ui[k];
  src[b*256+n] = acc;
}

// ------- cross-attn constant: cc[l][b] = Wo_ca @ (Wv_ca@src_b + bv) + bo --
__global__ void k_cc(const float* __restrict__ caW, const float* __restrict__ cab,
                     const float* __restrict__ caWo, const float* __restrict__ cabo,
                     const float* __restrict__ src, float* __restrict__ cc){
  int l = blockIdx.x >> 7, b = blockIdx.x & 127, t = threadIdx.x;
  __shared__ float v[256];
  const float* s = src + b*256;
  {
    const float* w = caW + ((long long)l*768 + 512 + t)*256;
    float a = cab[l*768 + 512 + t];
    #pragma unroll 8
    for (int k = 0; k < 256; ++k) a += w[k]*s[k];
    v[t] = a;
  }
  __syncthreads();
  {
    const float* w = caWo + ((long long)l*256 + t)*256;
    float a = cabo[l*256 + t];
    #pragma unroll 8
    for (int k = 0; k < 256; ++k) a += w[k]*v[k];
    cc[((long long)l*128 + b)*256 + t] = a;
  }
}

// ---------------- main decode kernel -------------------------------------
__global__ __launch_bounds__(512, 1) void k_main(
  const unsigned short* __restrict__ wqkv,   // [12][768][256] bf16
  const unsigned short* __restrict__ wo,     // [12][256][256]
  const unsigned short* __restrict__ wl1,    // [12][1024][256]
  const unsigned short* __restrict__ wl2,    // [12][256][1024]
  const float* __restrict__ bqkv, const float* __restrict__ bo_,
  const float* __restrict__ bl1,  const float* __restrict__ bl2,
  const float* __restrict__ g1, const float* __restrict__ be1,
  const float* __restrict__ g2, const float* __restrict__ be2,
  const float* __restrict__ g3, const float* __restrict__ be3,
  const float* __restrict__ cc,              // [12][128][256]
  const float* __restrict__ src,             // [128][256]
  const float* __restrict__ pos,             // [17][256]
  const float* __restrict__ outW,            // [4][256]
  const float* __restrict__ outb,
  const float* __restrict__ plow, const float* __restrict__ phigh,
  unsigned short* __restrict__ cache,        // [128][12][16][512] bf16 (k|v)
  float* __restrict__ out)                   // [128][16][4]
{
  __shared__ float xf[16*LDW];            // running x (f32, residual source)
  __shared__ float zs[16*LDW];            // pre-LN scratch
  __shared__ float ys[16*LDW];            // y (post-LN2, FFN residual)
  __shared__ unsigned short xb[16*LDW];   // bf16 A-operand (x, then y, then x')
  __shared__ unsigned short qs[16*LDW];   // q bf16
  __shared__ unsigned short ob[16*LDW];   // attn out bf16
  __shared__ unsigned short hb[16*LDH];   // relu(lin1) bf16

  const int tid = threadIdx.x;
  const int w = tid >> 6, lane = tid & 63;
  const int blk = blockIdx.x;
  const int mrow = lane & 15, kgrp = lane >> 4;

  // init: x = src + pos[0]
  {
    int row = tid >> 5, c8 = (tid & 31) * 8;
    const float* sp = src + (blk*16 + row)*256 + c8;
    const float* pp = pos + c8;
    #pragma unroll
    for (int k = 0; k < 8; ++k){
      float v = sp[k] + pp[k];
      xf[row*LDW + c8 + k] = v;
      xb[row*LDW + c8 + k] = f2b(v);
    }
  }
  __syncthreads();

  for (int i = 0; i < 16; ++i){
    for (int l = 0; l < 12; ++l){
      // ================= QKV projection =================
      {
        short8 a[8];
        #pragma unroll
        for (int kc = 0; kc < 8; ++kc)
          a[kc] = *(const short8*)&xb[mrow*LDW + kc*32 + kgrp*8];
        const unsigned short* wl = wqkv + (long long)l*768*256;
        const float* bl = bqkv + l*768;
        #pragma unroll
        for (int tp = 0; tp < 3; ++tp){
          int nt0 = w*6 + tp*2, nt1 = nt0 + 1;
          f32x4 acc0 = {0,0,0,0}, acc1 = {0,0,0,0};
          const unsigned short* w0 = wl + (nt0*16 + mrow)*256 + kgrp*8;
          const unsigned short* w1 = wl + (nt1*16 + mrow)*256 + kgrp*8;
          #pragma unroll
          for (int kc = 0; kc < 8; ++kc){
            short8 b0 = *(const short8*)(w0 + kc*32);
            short8 b1 = *(const short8*)(w1 + kc*32);
            acc0 = __builtin_amdgcn_mfma_f32_16x16x32_bf16(a[kc], b0, acc0, 0,0,0);
            acc1 = __builtin_amdgcn_mfma_f32_16x16x32_bf16(a[kc], b1, acc1, 0,0,0);
          }
          #pragma unroll
          for (int u = 0; u < 2; ++u){
            f32x4 acc = u ? acc1 : acc0;
            int nt = u ? nt1 : nt0;
            int n = nt*16 + mrow;
            float bias = bl[n];
            if (nt < 16){                       // q -> LDS
              #pragma unroll
              for (int r = 0; r < 4; ++r)
                qs[(kgrp*4 + r)*LDW + n] = f2b(acc[r] + bias);
            } else {                            // k,v -> global cache
              int c = (nt-16)*16 + mrow;        // 0..511 (k:0..255, v:256..511)
              #pragma unroll
              for (int r = 0; r < 4; ++r){
                int g = blk*16 + kgrp*4 + r;
                cache[(((long long)g*12 + l)*16 + i)*512 + c] = f2b(acc[r] + bias);
              }
            }
          }
        }
      }
      __syncthreads();
      // ================= self-attention (VALU) =================
      {
        int head = w >> 1;
        int row = (w & 1)*8 + (lane >> 3);
        int d0 = (lane & 7)*8;
        int g = blk*16 + row;
        float q[8];
        {
          const unsigned short* qp = &qs[row*LDW + head*64 + d0];
          #pragma unroll
          for (int t = 0; t < 8; ++t) q[t] = b2f(qp[t]);
        }
        const unsigned short* cb = cache + (((long long)g*12 + l)*16)*512 + head*64 + d0;
        float s[16];
        #pragma unroll
        for (int j = 0; j < 16; ++j){
          if (j <= i){
            const unsigned short* kp = cb + j*512;
            float p = 0.f;
            #pragma unroll
            for (int t = 0; t < 8; ++t) p += q[t]*b2f(kp[t]);
            p += __shfl_xor(p, 1);
            p += __shfl_xor(p, 2);
            p += __shfl_xor(p, 4);
            s[j] = p * 0.125f;                  // 1/sqrt(64)
          } else s[j] = -1e30f;
        }
        float mx = s[0];
        #pragma unroll
        for (int j = 1; j < 16; ++j) mx = fmaxf(mx, s[j]);
        float den = 0.f, e[16];
        #pragma unroll
        for (int j = 0; j < 16; ++j){ e[j] = __expf(s[j]-mx); den += e[j]; }
        float rden = 1.f/den;
        float o[8] = {0,0,0,0,0,0,0,0};
        #pragma unroll
        for (int j = 0; j < 16; ++j){
          if (j <= i){
            const unsigned short* vp = cb + j*512 + 256;
            float ej = e[j];
            #pragma unroll
            for (int t = 0; t < 8; ++t) o[t] += ej*b2f(vp[t]);
          }
        }
        unsigned short* op = &ob[row*LDW + head*64 + d0];
        #pragma unroll
        for (int t = 0; t < 8; ++t) op[t] = f2b(o[t]*rden);
      }
      __syncthreads();
      // ================= Wo + residual -> zs =================
      {
        short8 a[8];
        #pragma unroll
        for (int kc = 0; kc < 8; ++kc)
          a[kc] = *(const short8*)&ob[mrow*LDW + kc*32 + kgrp*8];
        const unsigned short* wl = wo + (long long)l*256*256;
        const float* bl = bo_ + l*256;
        int nt0 = w*2, nt1 = nt0+1;
        f32x4 acc0={0,0,0,0}, acc1={0,0,0,0};
        const unsigned short* w0 = wl + (nt0*16+mrow)*256 + kgrp*8;
        const unsigned short* w1 = wl + (nt1*16+mrow)*256 + kgrp*8;
        #pragma unroll
        for (int kc = 0; kc < 8; ++kc){
          short8 b0 = *(const short8*)(w0 + kc*32);
          short8 b1 = *(const short8*)(w1 + kc*32);
          acc0 = __builtin_amdgcn_mfma_f32_16x16x32_bf16(a[kc], b0, acc0, 0,0,0);
          acc1 = __builtin_amdgcn_mfma_f32_16x16x32_bf16(a[kc], b1, acc1, 0,0,0);
        }
        #pragma unroll
        for (int u = 0; u < 2; ++u){
          f32x4 acc = u?acc1:acc0; int nt = u?nt1:nt0;
          int n = nt*16+mrow; float bias = bl[n];
          #pragma unroll
          for (int r = 0; r < 4; ++r){
            int m = kgrp*4+r;
            zs[m*LDW+n] = acc[r] + bias + xf[m*LDW+n];
          }
        }
      }
      __syncthreads();
      // ================= LN1 + cross-const + LN2 -> ys, xb =================
      {
        int row = 2*w + (lane>>5), c8 = (lane&31)*8;
        int g = blk*16+row;
        float z[8];
        #pragma unroll
        for (int k = 0; k < 8; ++k) z[k] = zs[row*LDW+c8+k];
        float sm=0, sq=0;
        #pragma unroll
        for (int k = 0; k < 8; ++k){ sm += z[k]; sq += z[k]*z[k]; }
        #pragma unroll
        for (int d = 1; d < 32; d <<= 1){ sm += __shfl_xor(sm,d); sq += __shfl_xor(sq,d); }
        float mean = sm*(1.f/256), var = sq*(1.f/256)-mean*mean;
        float rs = rsqrtf(var + EPS_);
        const float* g1p = g1 + l*256 + c8;
        const float* b1p = be1 + l*256 + c8;
        const float* ccp = cc + ((long long)l*128+g)*256 + c8;
        float t2[8];
        #pragma unroll
        for (int k = 0; k < 8; ++k)
          t2[k] = (z[k]-mean)*rs*g1p[k] + b1p[k] + ccp[k];
        sm=0; sq=0;
        #pragma unroll
        for (int k = 0; k < 8; ++k){ sm += t2[k]; sq += t2[k]*t2[k]; }
        #pragma unroll
        for (int d = 1; d < 32; d <<= 1){ sm += __shfl_xor(sm,d); sq += __shfl_xor(sq,d); }
        mean = sm*(1.f/256); var = sq*(1.f/256)-mean*mean;
        rs = rsqrtf(var + EPS_);
        const float* g2p = g2 + l*256 + c8;
        const float* b2p = be2 + l*256 + c8;
        #pragma unroll
        for (int k = 0; k < 8; ++k){
          float y = (t2[k]-mean)*rs*g2p[k] + b2p[k];
          ys[row*LDW+c8+k] = y;
          xb[row*LDW+c8+k] = f2b(y);
        }
      }
      __syncthreads();
      // ================= lin1 + relu -> hb =================
      {
        short8 a[8];
        #pragma unroll
        for (int kc = 0; kc < 8; ++kc)
          a[kc] = *(const short8*)&xb[mrow*LDW + kc*32 + kgrp*8];
        const unsigned short* wl = wl1 + (long long)l*1024*256;
        const float* bl = bl1 + l*1024;
        #pragma unroll
        for (int tp = 0; tp < 4; ++tp){
          int nt0 = w*8 + tp*2, nt1 = nt0+1;
          f32x4 acc0={0,0,0,0}, acc1={0,0,0,0};
          const unsigned short* w0 = wl + (nt0*16+mrow)*256 + kgrp*8;
          const unsigned short* w1 = wl + (nt1*16+mrow)*256 + kgrp*8;
          #pragma unroll
          for (int kc = 0; kc < 8; ++kc){
            short8 b0 = *(const short8*)(w0+kc*32);
            short8 b1 = *(const short8*)(w1+kc*32);
            acc0 = __builtin_amdgcn_mfma_f32_16x16x32_bf16(a[kc], b0, acc0, 0,0,0);
            acc1 = __builtin_amdgcn_mfma_f32_16x16x32_bf16(a[kc], b1, acc1, 0,0,0);
          }
          #pragma unroll
          for (int u = 0; u < 2; ++u){
            f32x4 acc = u?acc1:acc0; int nt = u?nt1:nt0;
            int n = nt*16+mrow; float bias = bl[n];
            #pragma unroll
            for (int r = 0; r < 4; ++r){
              float h = acc[r]+bias;
              hb[(kgrp*4+r)*LDH + n] = f2b(h > 0.f ? h : 0.f);
            }
          }
        }
      }
      __syncthreads();
      // ================= lin2 + residual -> zs =================
      {
        const unsigned short* wl = wl2 + (long long)l*256*1024;
        const float* bl = bl2 + l*256;
        int nt0 = w*2, nt1 = nt0+1;
        f32x4 acc0={0,0,0,0}, acc1={0,0,0,0};
        const unsigned short* w0 = wl + (nt0*16+mrow)*1024 + kgrp*8;
        const unsigned short* w1 = wl + (nt1*16+mrow)*1024 + kgrp*8;
        #pragma unroll
        for (int kc = 0; kc < 32; ++kc){
          short8 a = *(const short8*)&hb[mrow*LDH + kc*32 + kgrp*8];
          short8 b0 = *(const short8*)(w0 + kc*32);
          short8 b1 = *(const short8*)(w1 + kc*32);
          acc0 = __builtin_amdgcn_mfma_f32_16x16x32_bf16(a, b0, acc0, 0,0,0);
          acc1 = __builtin_amdgcn_mfma_f32_16x16x32_bf16(a, b1, acc1, 0,0,0);
        }
        #pragma unroll
        for (int u = 0; u < 2; ++u){
          f32x4 acc = u?acc1:acc0; int nt = u?nt1:nt0;
          int n = nt*16+mrow; float bias = bl[n];
          #pragma unroll
          for (int r = 0; r < 4; ++r){
            int m = kgrp*4+r;
            zs[m*LDW+n] = acc[r] + bias + ys[m*LDW+n];
          }
        }
      }
      __syncthreads();
      // ================= LN3 -> xf, xb (+ step end) =================
      {
        int row = 2*w + (lane>>5), c8 = (lane&31)*8;
        int g = blk*16+row;
        float z[8];
        #pragma unroll
        for (int k = 0; k < 8; ++k) z[k] = zs[row*LDW+c8+k];
        float sm=0, sq=0;
        #pragma unroll
        for (int k = 0; k < 8; ++k){ sm += z[k]; sq += z[k]*z[k]; }
        #pragma unroll
        for (int d = 1; d < 32; d <<= 1){ sm += __shfl_xor(sm,d); sq += __shfl_xor(sq,d); }
        float mean = sm*(1.f/256), var = sq*(1.f/256)-mean*mean;
        float rs = rsqrtf(var + EPS_);
        const float* g3p = g3 + l*256 + c8;
        const float* b3p = be3 + l*256 + c8;
        float xn[8];
        #pragma unroll
        for (int k = 0; k < 8; ++k)
          xn[k] = (z[k]-mean)*rs*g3p[k] + b3p[k];
        if (l == 11){
          // output head: out = low + (high-low)*sigmoid(xn @ outW.T + outb)
          float pr[4];
          #pragma unroll
          for (int p = 0; p < 4; ++p){
            float a = 0;
            #pragma unroll
            for (int k = 0; k < 8; ++k) a += xn[k]*outW[p*256 + c8 + k];
            #pragma unroll
            for (int d = 1; d < 32; d <<= 1) a += __shfl_xor(a, d);
            pr[p] = a;
          }
          if ((lane & 31) == 0){
            #pragma unroll
            for (int p = 0; p < 4; ++p){
              float t = pr[p] + outb[p];
              float sg = 1.f/(1.f + __expf(-t));
              out[(g*16 + i)*4 + p] = plow[p] + (phigh[p]-plow[p])*sg;
            }
          }
          if (i < 15){   // next token input = seq[i+1] + pos[i+1]
            const float* pp = pos + (i+1)*256 + c8;
            #pragma unroll
            for (int k = 0; k < 8; ++k) xn[k] += pp[k];
          }
        }
        #pragma unroll
        for (int k = 0; k < 8; ++k){
          xf[row*LDW+c8+k] = xn[k];
          xb[row*LDW+c8+k] = f2b(xn[k]);
        }
      }
      __syncthreads();
    }
  }
}

extern "C" void kernel_launch(void* const* d_in, const int* in_sizes, int n_in,
                              void* d_out, int out_size, void* d_ws, size_t ws_size,
                              hipStream_t stream) {
  const float* U_real = (const float*)d_in[0];
  const float* U_imag = (const float*)d_in[1];
  const float* tok_W  = (const float*)d_in[2];
  const float* tok_b  = (const float*)d_in[3];
  const float* pos    = (const float*)d_in[4];
  const float* saW    = (const float*)d_in[5];
  const float* sab    = (const float*)d_in[6];
  const float* saWo   = (const float*)d_in[7];
  const float* sabo   = (const float*)d_in[8];
  const float* caW    = (const float*)d_in[9];
  const float* cab    = (const float*)d_in[10];
  const float* caWo   = (const float*)d_in[11];
  const float* cabo   = (const float*)d_in[12];
  const float* l1W    = (const float*)d_in[13];
  const float* l1b    = (const float*)d_in[14];
  const float* l2W    = (const float*)d_in[15];
  const float* l2b    = (const float*)d_in[16];
  const float* g1     = (const float*)d_in[17];
  const float* be1    = (const float*)d_in[18];
  const float* g2     = (const float*)d_in[19];
  const float* be2    = (const float*)d_in[20];
  const float* g3     = (const float*)d_in[21];
  const float* be3    = (const float*)d_in[22];
  const float* outW   = (const float*)d_in[23];
  const float* outb   = (const float*)d_in[24];
  const float* plow   = (const float*)d_in[25];
  const float* phigh  = (const float*)d_in[26];

  char* ws = (char*)d_ws;
  unsigned short* wb   = (unsigned short*)(ws + OFF_WQKV);
  float* srcb          = (float*)(ws + OFF_SRC);
  float* ccb           = (float*)(ws + OFF_CC);
  unsigned short* cache= (unsigned short*)(ws + OFF_CACHE);

  k_conv<<<dim3(4608), dim3(256), 0, stream>>>(saW, saWo, l1W, l2W, wb);
  k_src<<<dim3(128), dim3(256), 0, stream>>>(U_real, U_imag, tok_W, tok_b, srcb);
  k_cc<<<dim3(1536), dim3(256), 0, stream>>>(caW, cab, caWo, cabo, srcb, ccb);
  k_main<<<dim3(8), dim3(512), 0, stream>>>(
      wb,
      (unsigned short*)(ws + OFF_WO),
      (unsigned short*)(ws + OFF_L1),
      (unsigned short*)(ws + OFF_L2),
      sab, sabo, l1b, l2b,
      g1, be1, g2, be2, g3, be3,
      ccb, srcb, pos, outW, outb, plow, phigh,
      cache, (float*)d_out);
}

// Round 3
// 7482.267 us; speedup vs baseline: 1.4568x; 1.4568x over previous
//
#include <hip/hip_runtime.h>
#include <hip/hip_bf16.h>

// ---------------------------------------------------------------------------
// CompositePulseTransformerDecoder — MI355X (gfx950), round 3
// KV-cached incremental decode + cross-attn collapsed to constant.
// 32 blocks = 8 chains x 4 N-slices. Block (c,s) = blockIdx s*8+c so all
// slices of a chain share an XCD (bid%8). Per layer: block computes head s's
// q/k/v + local attention, then 4 flag-synced exchanges (o, z, h, z2) via ws.
// LN passes are computed redundantly (full row) by every block to save syncs.
// FIX vs round 2: KV cache has its layer dimension back ([128][12][4][16][128]);
// cc stored bf16 to keep ws footprint within the proven 45.7 MB.
// ---------------------------------------------------------------------------

typedef __attribute__((ext_vector_type(8))) short short8;
typedef __attribute__((ext_vector_type(4))) float f32x4;

#define EPS_ 1e-5f

__device__ __forceinline__ unsigned short f2b(float x){
  union { float f; unsigned u; } c; c.f = x;
  unsigned r = (c.u + 0x7fffu + ((c.u >> 16) & 1u)) >> 16;
  return (unsigned short)r;
}
__device__ __forceinline__ float b2f(unsigned short u){
  union { unsigned u; float f; } c; c.u = ((unsigned)u) << 16;
  return c.f;
}

// ws layout (bytes) — total 45,548,032 (round 1 proved >= 45,744,128 available)
#define OFF_WQKV 0ull            // 12*768*256  bf16 = 4,718,592
#define OFF_WO   4718592ull      // 12*256*256  bf16 = 1,572,864
#define OFF_L1   6291456ull      // 12*1024*256 bf16 = 6,291,456
#define OFF_L2   12582912ull     // 12*256*1024 bf16 = 6,291,456
#define OFF_SRC  18874368ull     // 128*256 f32 = 131,072
#define OFF_CC   19005440ull     // 12*128*256 bf16 = 786,432
#define OFF_KV   19791872ull     // 128*12*4*16*128 bf16 = 25,165,824
#define OFF_OBUF 44957696ull     // 8*4*16*64 bf16 = 65,536
#define OFF_ZBUF 45023232ull     // 8*4*16*64 f32 = 131,072
#define OFF_HBUF 45154304ull     // 8*4*16*256 bf16 = 262,144
#define OFF_Z2B  45416448ull     // 8*4*16*64 f32 = 131,072
#define OFF_FLAGS 45547520ull    // 4 types * 32 ints = 512

// ---------------- weight f32 -> bf16 conversion --------------------------
__global__ void k_conv(const float* __restrict__ wqkv, const float* __restrict__ wo,
                       const float* __restrict__ l1, const float* __restrict__ l2,
                       unsigned short* __restrict__ dst){
  const long long n0 = 12LL*768*256;
  const long long n1 = n0 + 12LL*256*256;
  const long long n2 = n1 + 12LL*1024*256;
  const long long n3 = n2 + 12LL*256*1024;
  for (long long idx = (long long)blockIdx.x*256 + threadIdx.x; idx < n3;
       idx += (long long)gridDim.x*256){
    float v;
    if (idx < n0) v = wqkv[idx];
    else if (idx < n1) v = wo[idx - n0];
    else if (idx < n2) v = l1[idx - n1];
    else v = l2[idx - n2];
    dst[idx] = f2b(v);
  }
}

// ---------------- src = vec @ tok_W.T + tok_b ----------------------------
__global__ void k_src(const float* __restrict__ U_real, const float* __restrict__ U_imag,
                      const float* __restrict__ tok_W, const float* __restrict__ tok_b,
                      float* __restrict__ src){
  int b = blockIdx.x, n = threadIdx.x;
  const float* w = tok_W + n*128;
  const float* ur = U_real + b*64;
  const float* ui = U_imag + b*64;
  float acc = tok_b[n];
  #pragma unroll 8
  for (int k = 0; k < 64; ++k) acc += w[k]*ur[k];
  #pragma unroll 8
  for (int k = 0; k < 64; ++k) acc += w[64+k]*ui[k];
  src[b*256+n] = acc;
}

// ------- cross-attn constant: cc[l][b] = Wo_ca @ (Wv_ca@src_b + bv) + bo --
__global__ void k_cc(const float* __restrict__ caW, const float* __restrict__ cab,
                     const float* __restrict__ caWo, const float* __restrict__ cabo,
                     const float* __restrict__ src, unsigned short* __restrict__ cc){
  int l = blockIdx.x >> 7, b = blockIdx.x & 127, t = threadIdx.x;
  __shared__ float v[256];
  const float* s = src + b*256;
  {
    const float* w = caW + ((long long)l*768 + 512 + t)*256;
    float a = cab[l*768 + 512 + t];
    #pragma unroll 8
    for (int k = 0; k < 256; ++k) a += w[k]*s[k];
    v[t] = a;
  }
  __syncthreads();
  {
    const float* w = caWo + ((long long)l*256 + t)*256;
    float a = cabo[l*256 + t];
    #pragma unroll 8
    for (int k = 0; k < 256; ++k) a += w[k]*v[k];
    cc[((long long)l*128 + b)*256 + t] = f2b(a);
  }
}

// ---------------- main decode kernel -------------------------------------
// publish own flag, wait for 3 peers (same chain), with agent-scope ordering
#define PUBWAIT(TYPE) do{                                                    \
  __threadfence();                                                           \
  __syncthreads();                                                           \
  if (tid == 0)                                                              \
    __hip_atomic_store(flags + (TYPE)*32 + c*4 + s, seq,                     \
        __ATOMIC_RELEASE, __HIP_MEMORY_SCOPE_AGENT);                         \
  if (tid < 3){                                                              \
    int so = tid + (tid >= s ? 1 : 0);                                       \
    while (__hip_atomic_load(flags + (TYPE)*32 + c*4 + so,                   \
        __ATOMIC_ACQUIRE, __HIP_MEMORY_SCOPE_AGENT) < seq)                   \
      __builtin_amdgcn_s_sleep(1);                                           \
  }                                                                          \
  __syncthreads();                                                           \
}while(0)

__global__ __launch_bounds__(256, 1) void k_main(
  const unsigned short* __restrict__ wqkv,   // [12][768][256] bf16
  const unsigned short* __restrict__ wo,     // [12][256][256]
  const unsigned short* __restrict__ wl1,    // [12][1024][256]
  const unsigned short* __restrict__ wl2,    // [12][256][1024]
  const float* __restrict__ bqkv, const float* __restrict__ bo_,
  const float* __restrict__ bl1,  const float* __restrict__ bl2,
  const float* __restrict__ g1, const float* __restrict__ be1,
  const float* __restrict__ g2, const float* __restrict__ be2,
  const float* __restrict__ g3, const float* __restrict__ be3,
  const unsigned short* __restrict__ cc,     // [12][128][256] bf16
  const float* __restrict__ src,             // [128][256]
  const float* __restrict__ pos,             // [17][256]
  const float* __restrict__ outW,            // [4][256]
  const float* __restrict__ outb,
  const float* __restrict__ plow, const float* __restrict__ phigh,
  unsigned short* __restrict__ kvc,          // [128][12][4][16][128] bf16 (k|v)
  unsigned short* __restrict__ obuf,         // [8][4][16][64] bf16
  float* __restrict__ zbuf,                  // [8][4][16][64] f32
  unsigned short* __restrict__ hbuf,         // [8][4][16][256] bf16
  float* __restrict__ z2buf,                 // [8][4][16][64] f32
  int* __restrict__ flags,                   // [4][8][4]
  float* __restrict__ out)                   // [128][16][4]
{
  // padded strides: f32 rows 260 (=4*65, odd 16B blocks); bf16 rows 264 (=8*33)
  __shared__ float xf[16][260];            // running x (residual source)
  __shared__ float zf[16][260];            // exchanged z / z2
  __shared__ float yf[16][260];            // y (post-LN2, FFN residual)
  __shared__ unsigned short xb[16][264];   // bf16 A-operand (x, then y)
  __shared__ unsigned short ob[16][264];   // full attn out bf16
  __shared__ unsigned short hb[16][1032];  // full relu(lin1) bf16
  __shared__ unsigned short qs[16][72];    // q slice (head s)

  const int tid  = threadIdx.x;
  const int w    = tid >> 6, lane = tid & 63;
  const int c    = blockIdx.x & 7;    // chain (XCD)
  const int s    = blockIdx.x >> 3;   // slice / head
  const int mrow = lane & 15, kgrp = lane >> 4;

  // init: x = src + pos[0]
  {
    int row = tid >> 4, c16 = (tid & 15) * 16;
    const float* sp = src + (c*16 + row)*256 + c16;
    const float* pp = pos + c16;
    #pragma unroll
    for (int k = 0; k < 16; ++k){
      float v = sp[k] + pp[k];
      xf[row][c16+k] = v;
      xb[row][c16+k] = f2b(v);
    }
  }
  __syncthreads();

  for (int i = 0; i < 16; ++i){
    for (int l = 0; l < 12; ++l){
      const int seq = i*12 + l + 1;
      // ========== QKV slice (head s): q,k,v each 16x64 ==========
      {
        short8 a[8];
        #pragma unroll
        for (int kc = 0; kc < 8; ++kc)
          a[kc] = *(const short8*)&xb[mrow][kc*32 + kgrp*8];
        const unsigned short* wl = wqkv + (size_t)l*768*256;
        const int n_l = w*16 + mrow;            // 0..63 within head slice
        const unsigned short* wp0 = wl + (size_t)(0*256 + s*64 + n_l)*256 + kgrp*8;
        const unsigned short* wp1 = wl + (size_t)(1*256 + s*64 + n_l)*256 + kgrp*8;
        const unsigned short* wp2 = wl + (size_t)(2*256 + s*64 + n_l)*256 + kgrp*8;
        f32x4 ac0 = {0,0,0,0}, ac1 = {0,0,0,0}, ac2 = {0,0,0,0};
        #pragma unroll
        for (int kc = 0; kc < 8; ++kc){
          short8 b0 = *(const short8*)(wp0 + kc*32);
          short8 b1 = *(const short8*)(wp1 + kc*32);
          short8 b2 = *(const short8*)(wp2 + kc*32);
          ac0 = __builtin_amdgcn_mfma_f32_16x16x32_bf16(a[kc], b0, ac0, 0,0,0);
          ac1 = __builtin_amdgcn_mfma_f32_16x16x32_bf16(a[kc], b1, ac1, 0,0,0);
          ac2 = __builtin_amdgcn_mfma_f32_16x16x32_bf16(a[kc], b2, ac2, 0,0,0);
        }
        float bq = bqkv[l*768 + 0*256 + s*64 + n_l];
        float bk = bqkv[l*768 + 1*256 + s*64 + n_l];
        float bv = bqkv[l*768 + 2*256 + s*64 + n_l];
        #pragma unroll
        for (int r = 0; r < 4; ++r){
          int row = kgrp*4 + r;
          qs[row][n_l] = f2b(ac0[r] + bq);
          size_t kb = ((size_t)(((c*16+row)*12 + l)*4 + s)*16 + i)*128;
          kvc[kb + n_l]      = f2b(ac1[r] + bk);
          kvc[kb + 64 + n_l] = f2b(ac2[r] + bv);
        }
      }
      __syncthreads();
      // ========== attention (head s, block-local KV) ==========
      {
        int row = w*4 + (lane >> 4);
        int lid = lane & 15;
        float q4[4];
        #pragma unroll
        for (int t = 0; t < 4; ++t) q4[t] = b2f(qs[row][lid*4 + t]);
        const unsigned short* base =
            kvc + ((size_t)(((c*16+row)*12 + l)*4 + s)*16)*128 + lid*4;
        float sv[16];
        #pragma unroll
        for (int j = 0; j < 16; ++j){
          if (j <= i){
            const unsigned short* kp = base + j*128;
            float p = 0.f;
            #pragma unroll
            for (int t = 0; t < 4; ++t) p += q4[t]*b2f(kp[t]);
            p += __shfl_xor(p, 1);
            p += __shfl_xor(p, 2);
            p += __shfl_xor(p, 4);
            p += __shfl_xor(p, 8);
            sv[j] = p * 0.125f;               // 1/sqrt(64)
          } else sv[j] = -1e30f;
        }
        float mx = sv[0];
        #pragma unroll
        for (int j = 1; j < 16; ++j) mx = fmaxf(mx, sv[j]);
        float den = 0.f, e[16];
        #pragma unroll
        for (int j = 0; j < 16; ++j){ e[j] = __expf(sv[j]-mx); den += e[j]; }
        float rd = 1.f/den;
        float o4[4] = {0,0,0,0};
        #pragma unroll
        for (int j = 0; j < 16; ++j){
          if (j <= i){
            const unsigned short* vp = base + j*128 + 64;
            float ej = e[j];
            #pragma unroll
            for (int t = 0; t < 4; ++t) o4[t] += ej*b2f(vp[t]);
          }
        }
        unsigned short* op = obuf + ((size_t)(c*4+s)*16 + row)*64 + lid*4;
        #pragma unroll
        for (int t = 0; t < 4; ++t) op[t] = f2b(o4[t]*rd);
      }
      PUBWAIT(0);
      // gather full o into LDS
      {
        int row = tid >> 4, c16 = (tid & 15)*16;
        int h = c16 >> 6, d = c16 & 63;
        const unsigned short* p = obuf + ((size_t)(c*4+h)*16 + row)*64 + d;
        *(short8*)&ob[row][c16]   = *(const short8*)p;
        *(short8*)&ob[row][c16+8] = *(const short8*)(p+8);
      }
      __syncthreads();
      // ========== Wo slice + residual -> zbuf ==========
      {
        short8 a[8];
        #pragma unroll
        for (int kc = 0; kc < 8; ++kc)
          a[kc] = *(const short8*)&ob[mrow][kc*32 + kgrp*8];
        const int n_l = w*16 + mrow, n_g = s*64 + n_l;
        const unsigned short* wp = wo + (size_t)l*65536 + (size_t)n_g*256 + kgrp*8;
        f32x4 acc = {0,0,0,0};
        #pragma unroll
        for (int kc = 0; kc < 8; ++kc){
          short8 b0 = *(const short8*)(wp + kc*32);
          acc = __builtin_amdgcn_mfma_f32_16x16x32_bf16(a[kc], b0, acc, 0,0,0);
        }
        float bias = bo_[l*256 + n_g];
        #pragma unroll
        for (int r = 0; r < 4; ++r){
          int row = kgrp*4 + r;
          zbuf[((size_t)(c*4+s)*16 + row)*64 + n_l] = acc[r] + bias + xf[row][n_g];
        }
      }
      PUBWAIT(1);
      // gather full z
      {
        int row = tid >> 4, c16 = (tid & 15)*16;
        int sl = c16 >> 6, d = c16 & 63;
        const float* p = zbuf + ((size_t)(c*4+sl)*16 + row)*64 + d;
        #pragma unroll
        for (int q = 0; q < 4; ++q)
          *(f32x4*)&zf[row][c16 + q*4] = *(const f32x4*)(p + q*4);
      }
      __syncthreads();
      // ========== LN1 + cc + LN2 (redundant full rows) ==========
      {
        int row = w*4 + (lane >> 4), c16 = (lane & 15)*16;
        float t[16];
        #pragma unroll
        for (int q = 0; q < 4; ++q)
          *(f32x4*)&t[q*4] = *(const f32x4*)&zf[row][c16 + q*4];
        float sm = 0, sq = 0;
        #pragma unroll
        for (int k = 0; k < 16; ++k){ sm += t[k]; sq += t[k]*t[k]; }
        sm += __shfl_xor(sm,1); sq += __shfl_xor(sq,1);
        sm += __shfl_xor(sm,2); sq += __shfl_xor(sq,2);
        sm += __shfl_xor(sm,4); sq += __shfl_xor(sq,4);
        sm += __shfl_xor(sm,8); sq += __shfl_xor(sq,8);
        float mean = sm*(1.f/256), var = sq*(1.f/256) - mean*mean;
        float rs = rsqrtf(var + EPS_);
        const float* g1p = g1 + l*256 + c16;
        const float* b1p = be1 + l*256 + c16;
        const unsigned short* ccp = cc + ((size_t)l*128 + c*16 + row)*256 + c16;
        #pragma unroll
        for (int k = 0; k < 16; ++k)
          t[k] = (t[k]-mean)*rs*g1p[k] + b1p[k] + b2f(ccp[k]);
        sm = 0; sq = 0;
        #pragma unroll
        for (int k = 0; k < 16; ++k){ sm += t[k]; sq += t[k]*t[k]; }
        sm += __shfl_xor(sm,1); sq += __shfl_xor(sq,1);
        sm += __shfl_xor(sm,2); sq += __shfl_xor(sq,2);
        sm += __shfl_xor(sm,4); sq += __shfl_xor(sq,4);
        sm += __shfl_xor(sm,8); sq += __shfl_xor(sq,8);
        mean = sm*(1.f/256); var = sq*(1.f/256) - mean*mean;
        rs = rsqrtf(var + EPS_);
        const float* g2p = g2 + l*256 + c16;
        const float* b2p = be2 + l*256 + c16;
        #pragma unroll
        for (int k = 0; k < 16; ++k){
          float y = (t[k]-mean)*rs*g2p[k] + b2p[k];
          yf[row][c16+k] = y;
          xb[row][c16+k] = f2b(y);
        }
      }
      __syncthreads();
      // ========== lin1 slice (256 of 1024) + relu -> hbuf ==========
      {
        short8 a[8];
        #pragma unroll
        for (int kc = 0; kc < 8; ++kc)
          a[kc] = *(const short8*)&xb[mrow][kc*32 + kgrp*8];
        const unsigned short* wl = wl1 + (size_t)l*262144;
        f32x4 acc[4] = {{0,0,0,0},{0,0,0,0},{0,0,0,0},{0,0,0,0}};
        const unsigned short* wp[4];
        #pragma unroll
        for (int tp = 0; tp < 4; ++tp){
          int n_g = s*256 + (w*4+tp)*16 + mrow;
          wp[tp] = wl + (size_t)n_g*256 + kgrp*8;
        }
        #pragma unroll
        for (int kc = 0; kc < 8; ++kc){
          #pragma unroll
          for (int tp = 0; tp < 4; ++tp){
            short8 b0 = *(const short8*)(wp[tp] + kc*32);
            acc[tp] = __builtin_amdgcn_mfma_f32_16x16x32_bf16(a[kc], b0, acc[tp], 0,0,0);
          }
        }
        #pragma unroll
        for (int tp = 0; tp < 4; ++tp){
          int n_sl = (w*4+tp)*16 + mrow;          // 0..255 within slice
          float bias = bl1[l*1024 + s*256 + n_sl];
          #pragma unroll
          for (int r = 0; r < 4; ++r){
            int row = kgrp*4 + r;
            float h = acc[tp][r] + bias;
            hbuf[((size_t)(c*4+s)*16 + row)*256 + n_sl] = f2b(h > 0.f ? h : 0.f);
          }
        }
      }
      PUBWAIT(2);
      // gather full h
      {
        int row = tid >> 4, col = (tid & 15)*64;
        int sl = col >> 8, d = col & 255;
        const unsigned short* p = hbuf + ((size_t)(c*4+sl)*16 + row)*256 + d;
        #pragma unroll
        for (int q = 0; q < 8; ++q)
          *(short8*)&hb[row][col + q*8] = *(const short8*)(p + q*8);
      }
      __syncthreads();
      // ========== lin2 slice + residual -> z2buf ==========
      {
        const int n_l = w*16 + mrow, n_g = s*64 + n_l;
        const unsigned short* wp = wl2 + (size_t)l*262144 + (size_t)n_g*1024 + kgrp*8;
        f32x4 acc = {0,0,0,0};
        #pragma unroll
        for (int kc = 0; kc < 32; ++kc){
          short8 a = *(const short8*)&hb[mrow][kc*32 + kgrp*8];
          short8 b0 = *(const short8*)(wp + kc*32);
          acc = __builtin_amdgcn_mfma_f32_16x16x32_bf16(a, b0, acc, 0,0,0);
        }
        float bias = bl2[l*256 + n_g];
        #pragma unroll
        for (int r = 0; r < 4; ++r){
          int row = kgrp*4 + r;
          z2buf[((size_t)(c*4+s)*16 + row)*64 + n_l] = acc[r] + bias + yf[row][n_g];
        }
      }
      PUBWAIT(3);
      // gather full z2
      {
        int row = tid >> 4, c16 = (tid & 15)*16;
        int sl = c16 >> 6, d = c16 & 63;
        const float* p = z2buf + ((size_t)(c*4+sl)*16 + row)*64 + d;
        #pragma unroll
        for (int q = 0; q < 4; ++q)
          *(f32x4*)&zf[row][c16 + q*4] = *(const f32x4*)(p + q*4);
      }
      __syncthreads();
      // ========== LN3 (redundant full rows) + step tail ==========
      {
        int row = w*4 + (lane >> 4), c16 = (lane & 15)*16;
        float t[16];
        #pragma unroll
        for (int q = 0; q < 4; ++q)
          *(f32x4*)&t[q*4] = *(const f32x4*)&zf[row][c16 + q*4];
        float sm = 0, sq = 0;
        #pragma unroll
        for (int k = 0; k < 16; ++k){ sm += t[k]; sq += t[k]*t[k]; }
        sm += __shfl_xor(sm,1); sq += __shfl_xor(sq,1);
        sm += __shfl_xor(sm,2); sq += __shfl_xor(sq,2);
        sm += __shfl_xor(sm,4); sq += __shfl_xor(sq,4);
        sm += __shfl_xor(sm,8); sq += __shfl_xor(sq,8);
        float mean = sm*(1.f/256), var = sq*(1.f/256) - mean*mean;
        float rs = rsqrtf(var + EPS_);
        const float* g3p = g3 + l*256 + c16;
        const float* b3p = be3 + l*256 + c16;
        float xn[16];
        #pragma unroll
        for (int k = 0; k < 16; ++k)
          xn[k] = (t[k]-mean)*rs*g3p[k] + b3p[k];
        if (l == 11){
          if (s == 0){
            float pr[4];
            #pragma unroll
            for (int p = 0; p < 4; ++p){
              float a = 0.f;
              #pragma unroll
              for (int k = 0; k < 16; ++k) a += xn[k]*outW[p*256 + c16 + k];
              a += __shfl_xor(a,1); a += __shfl_xor(a,2);
              a += __shfl_xor(a,4); a += __shfl_xor(a,8);
              pr[p] = a;
            }
            if ((lane & 15) == 0){
              #pragma unroll
              for (int p = 0; p < 4; ++p){
                float tt = pr[p] + outb[p];
                float sg = 1.f/(1.f + __expf(-tt));
                out[((size_t)(c*16+row)*16 + i)*4 + p] = plow[p] + (phigh[p]-plow[p])*sg;
              }
            }
          }
          if (i < 15){
            const float* pp = pos + (i+1)*256 + c16;
            #pragma unroll
            for (int k = 0; k < 16; ++k) xn[k] += pp[k];
          }
        }
        #pragma unroll
        for (int k = 0; k < 16; ++k){
          xf[row][c16+k] = xn[k];
          xb[row][c16+k] = f2b(xn[k]);
        }
      }
      __syncthreads();
    }
  }
}

extern "C" void kernel_launch(void* const* d_in, const int* in_sizes, int n_in,
                              void* d_out, int out_size, void* d_ws, size_t ws_size,
                              hipStream_t stream) {
  const float* U_real = (const float*)d_in[0];
  const float* U_imag = (const float*)d_in[1];
  const float* tok_W  = (const float*)d_in[2];
  const float* tok_b  = (const float*)d_in[3];
  const float* pos    = (const float*)d_in[4];
  const float* saW    = (const float*)d_in[5];
  const float* sab    = (const float*)d_in[6];
  const float* saWo   = (const float*)d_in[7];
  const float* sabo   = (const float*)d_in[8];
  const float* caW    = (const float*)d_in[9];
  const float* cab    = (const float*)d_in[10];
  const float* caWo   = (const float*)d_in[11];
  const float* cabo   = (const float*)d_in[12];
  const float* l1W    = (const float*)d_in[13];
  const float* l1b    = (const float*)d_in[14];
  const float* l2W    = (const float*)d_in[15];
  const float* l2b    = (const float*)d_in[16];
  const float* g1     = (const float*)d_in[17];
  const float* be1    = (const float*)d_in[18];
  const float* g2     = (const float*)d_in[19];
  const float* be2    = (const float*)d_in[20];
  const float* g3     = (const float*)d_in[21];
  const float* be3    = (const float*)d_in[22];
  const float* outW   = (const float*)d_in[23];
  const float* outb   = (const float*)d_in[24];
  const float* plow   = (const float*)d_in[25];
  const float* phigh  = (const float*)d_in[26];

  char* ws = (char*)d_ws;
  unsigned short* wb    = (unsigned short*)(ws + OFF_WQKV);
  float* srcb           = (float*)(ws + OFF_SRC);
  unsigned short* ccb   = (unsigned short*)(ws + OFF_CC);
  unsigned short* kvc   = (unsigned short*)(ws + OFF_KV);
  unsigned short* obuf  = (unsigned short*)(ws + OFF_OBUF);
  float* zbuf           = (float*)(ws + OFF_ZBUF);
  unsigned short* hbuf  = (unsigned short*)(ws + OFF_HBUF);
  float* z2buf          = (float*)(ws + OFF_Z2B);
  int* flags            = (int*)(ws + OFF_FLAGS);

  hipMemsetAsync(ws + OFF_FLAGS, 0, 512, stream);
  k_conv<<<dim3(4608), dim3(256), 0, stream>>>(saW, saWo, l1W, l2W, wb);
  k_src<<<dim3(128), dim3(256), 0, stream>>>(U_real, U_imag, tok_W, tok_b, srcb);
  k_cc<<<dim3(1536), dim3(256), 0, stream>>>(caW, cab, caWo, cabo, srcb, ccb);
  k_main<<<dim3(32), dim3(256), 0, stream>>>(
      wb,
      (unsigned short*)(ws + OFF_WO),
      (unsigned short*)(ws + OFF_L1),
      (unsigned short*)(ws + OFF_L2),
      sab, sabo, l1b, l2b,
      g1, be1, g2, be2, g3, be3,
      ccb, srcb, pos, outW, outb, plow, phigh,
      kvc, obuf, zbuf, hbuf, z2buf, flags, (float*)d_out);
}

// Round 5
// 6088.062 us; speedup vs baseline: 1.7904x; 1.2290x over previous
//
#include <hip/hip_runtime.h>
#include <hip/hip_bf16.h>

// ---------------------------------------------------------------------------
// CompositePulseTransformerDecoder — MI355X (gfx950), round 5
// KV-cached incremental decode + cross-attn collapsed to constant.
// 32 blocks = 8 chains x 4 slices, 512 threads (8 waves) each.
// Per layer only TWO flag syncs:
//   phase A: QKV(head s) -> attention(head s) -> Wo K-split partial -> sync0
//            -> sum partials + LN1 + cc + LN2 (redundant full rows)
//   phase B: lin1 N-slice -> lin2 K-split partial -> sync1
//            -> sum partials + LN3 (redundant full rows)
// Sync: relaxed-agent spin + single agent acquire fence (builtin_amdgcn_fence).
// ---------------------------------------------------------------------------

typedef __attribute__((ext_vector_type(8))) short short8;
typedef __attribute__((ext_vector_type(4))) float f32x4;

#define EPS_ 1e-5f

__device__ __forceinline__ unsigned short f2b(float x){
  union { float f; unsigned u; } c; c.f = x;
  unsigned r = (c.u + 0x7fffu + ((c.u >> 16) & 1u)) >> 16;
  return (unsigned short)r;
}
__device__ __forceinline__ float b2f(unsigned short u){
  union { unsigned u; float f; } c; c.u = ((unsigned)u) << 16;
  return c.f;
}

// ws layout (bytes) — total end 45,482,496 (< 45,744,128 proven in round 1)
#define OFF_WQKV 0ull            // 12*768*256  bf16 = 4,718,592
#define OFF_WO   4718592ull      // 12*256*256  bf16 = 1,572,864
#define OFF_L1   6291456ull      // 12*1024*256 bf16 = 6,291,456
#define OFF_L2   12582912ull     // 12*256*1024 bf16 = 6,291,456
#define OFF_SRC  18874368ull     // 128*256 f32 = 131,072
#define OFF_CC   19005440ull     // 12*128*256 bf16 = 786,432
#define OFF_KV   19791872ull     // 128*12*4*16*128 bf16 = 25,165,824
#define OFF_ZBUFB 44957696ull    // Wo partials bf16: 8*4*16*256 = 262,144
#define OFF_FLAGS 45219840ull    // 512 B
#define OFF_Z2B16 45220352ull    // lin2 partials bf16: 8*4*16*256 = 262,144

// ---------------- weight f32 -> bf16 conversion --------------------------
__global__ void k_conv(const float* __restrict__ wqkv, const float* __restrict__ wo,
                       const float* __restrict__ l1, const float* __restrict__ l2,
                       unsigned short* __restrict__ dst){
  const long long n0 = 12LL*768*256;
  const long long n1 = n0 + 12LL*256*256;
  const long long n2 = n1 + 12LL*1024*256;
  const long long n3 = n2 + 12LL*256*1024;
  for (long long idx = (long long)blockIdx.x*256 + threadIdx.x; idx < n3;
       idx += (long long)gridDim.x*256){
    float v;
    if (idx < n0) v = wqkv[idx];
    else if (idx < n1) v = wo[idx - n0];
    else if (idx < n2) v = l1[idx - n1];
    else v = l2[idx - n2];
    dst[idx] = f2b(v);
  }
}

// ---------------- src = vec @ tok_W.T + tok_b ----------------------------
__global__ void k_src(const float* __restrict__ U_real, const float* __restrict__ U_imag,
                      const float* __restrict__ tok_W, const float* __restrict__ tok_b,
                      float* __restrict__ src){
  int b = blockIdx.x, n = threadIdx.x;
  const float* w = tok_W + n*128;
  const float* ur = U_real + b*64;
  const float* ui = U_imag + b*64;
  float acc = tok_b[n];
  #pragma unroll 8
  for (int k = 0; k < 64; ++k) acc += w[k]*ur[k];
  #pragma unroll 8
  for (int k = 0; k < 64; ++k) acc += w[64+k]*ui[k];
  src[b*256+n] = acc;
}

// ------- cross-attn constant: cc[l][b] = Wo_ca @ (Wv_ca@src_b + bv) + bo --
__global__ void k_cc(const float* __restrict__ caW, const float* __restrict__ cab,
                     const float* __restrict__ caWo, const float* __restrict__ cabo,
                     const float* __restrict__ src, unsigned short* __restrict__ cc){
  int l = blockIdx.x >> 7, b = blockIdx.x & 127, t = threadIdx.x;
  __shared__ float v[256];
  const float* s = src + b*256;
  {
    const float* w = caW + ((long long)l*768 + 512 + t)*256;
    float a = cab[l*768 + 512 + t];
    #pragma unroll 8
    for (int k = 0; k < 256; ++k) a += w[k]*s[k];
    v[t] = a;
  }
  __syncthreads();
  {
    const float* w = caWo + ((long long)l*256 + t)*256;
    float a = cabo[l*256 + t];
    #pragma unroll 8
    for (int k = 0; k < 256; ++k) a += w[k]*v[k];
    cc[((long long)l*128 + b)*256 + t] = f2b(a);
  }
}

// ---------------- main decode kernel -------------------------------------
// publish own flag (release), spin RELAXED on 3 peers, one acquire fence.
#define PUBWAIT(TYPE) do{                                                    \
  __syncthreads();                                                           \
  if (tid == 0)                                                              \
    __hip_atomic_store(flags + (TYPE)*32 + c*4 + s, seq,                     \
        __ATOMIC_RELEASE, __HIP_MEMORY_SCOPE_AGENT);                         \
  if (tid < 3){                                                              \
    int so = tid + (tid >= s ? 1 : 0);                                       \
    const int* fp = flags + (TYPE)*32 + c*4 + so;                            \
    while (__hip_atomic_load(fp, __ATOMIC_RELAXED,                           \
        __HIP_MEMORY_SCOPE_AGENT) < seq)                                     \
      __builtin_amdgcn_s_sleep(1);                                           \
  }                                                                          \
  __syncthreads();                                                           \
  __builtin_amdgcn_fence(__ATOMIC_ACQUIRE, "agent");                         \
}while(0)

__global__ __launch_bounds__(512, 1) void k_main(
  const unsigned short* __restrict__ wqkv,   // [12][768][256] bf16
  const unsigned short* __restrict__ wo,     // [12][256][256]
  const unsigned short* __restrict__ wl1,    // [12][1024][256]
  const unsigned short* __restrict__ wl2,    // [12][256][1024]
  const float* __restrict__ bqkv, const float* __restrict__ bo_,
  const float* __restrict__ bl1,  const float* __restrict__ bl2,
  const float* __restrict__ g1, const float* __restrict__ be1,
  const float* __restrict__ g2, const float* __restrict__ be2,
  const float* __restrict__ g3, const float* __restrict__ be3,
  const unsigned short* __restrict__ cc,     // [12][128][256] bf16
  const float* __restrict__ src,             // [128][256]
  const float* __restrict__ pos,             // [17][256]
  const float* __restrict__ outW,            // [4][256]
  const float* __restrict__ outb,
  const float* __restrict__ plow, const float* __restrict__ phigh,
  unsigned short* __restrict__ kvc,          // [128][12][4][16][128] bf16 (k|v)
  unsigned short* __restrict__ zbuf,         // [8][4][16][256] bf16 Wo partials
  unsigned short* __restrict__ z2buf,        // [8][4][16][256] bf16 lin2 partials
  int* __restrict__ flags,                   // [2][8][4] (+pad)
  float* __restrict__ out)                   // [128][16][4]
{
  __shared__ float xf[16][260];            // running x (residual source)
  __shared__ float yf[16][260];            // y (post-LN2, FFN residual)
  __shared__ unsigned short xb[16][264];   // bf16 A-operand (x / y)
  __shared__ unsigned short hs[16][264];   // relu(lin1) slice bf16
  __shared__ unsigned short qs[16][72];    // q slice (head s)
  __shared__ unsigned short os[16][72];    // attn out slice (head s)

  const int tid  = threadIdx.x;
  const int w    = tid >> 6, lane = tid & 63;
  const int c    = blockIdx.x & 7;    // chain
  const int s    = blockIdx.x >> 3;   // slice / head
  const int mrow = lane & 15, kgrp = lane >> 4;

  // init: x = src + pos[0]
  {
    int row = tid >> 5, c8 = (tid & 31) * 8;
    const float* sp = src + (c*16 + row)*256 + c8;
    const float* pp = pos + c8;
    #pragma unroll
    for (int k = 0; k < 8; ++k){
      float v = sp[k] + pp[k];
      xf[row][c8+k] = v;
      xb[row][c8+k] = f2b(v);
    }
  }
  __syncthreads();

  for (int i = 0; i < 16; ++i){
    for (int l = 0; l < 12; ++l){
      const int seq = i*12 + l + 1;
      // ===== A1: QKV (head s) — 12 N-tiles over 8 waves =====
      {
        short8 a[8];
        #pragma unroll
        for (int kc = 0; kc < 8; ++kc)
          a[kc] = *(const short8*)&xb[mrow][kc*32 + kgrp*8];
        const unsigned short* wl = wqkv + (size_t)l*768*256;
        for (int t = w; t < 12; t += 8){
          int p = t >> 2, tt = t & 3;
          int n_l = tt*16 + mrow;                 // 0..63 within head slice
          const unsigned short* wp = wl + (size_t)(p*256 + s*64 + n_l)*256 + kgrp*8;
          f32x4 acc = {0,0,0,0};
          #pragma unroll
          for (int kc = 0; kc < 8; ++kc){
            short8 b0 = *(const short8*)(wp + kc*32);
            acc = __builtin_amdgcn_mfma_f32_16x16x32_bf16(a[kc], b0, acc, 0,0,0);
          }
          float bias = bqkv[l*768 + p*256 + s*64 + n_l];
          #pragma unroll
          for (int r = 0; r < 4; ++r){
            int br = kgrp*4 + r;
            float v = acc[r] + bias;
            if (p == 0){
              qs[br][n_l] = f2b(v);
            } else {
              size_t kb = ((((size_t)(c*16+br)*12 + l)*4 + s)*16 + i)*128;
              kvc[kb + (p == 2 ? 64 : 0) + n_l] = f2b(v);
            }
          }
        }
      }
      __syncthreads();
      // ===== A2: attention (head s) — 8 waves x 2 rows, 32 lanes/row =====
      {
        int row = w*2 + (lane >> 5);
        int lid = lane & 31;
        float q0 = b2f(qs[row][lid*2]), q1 = b2f(qs[row][lid*2+1]);
        const unsigned short* base =
            kvc + ((((size_t)(c*16+row)*12 + l)*4 + s)*16)*128 + lid*2;
        float sv[16];
        #pragma unroll
        for (int j = 0; j < 16; ++j){
          if (j <= i){
            const unsigned short* kp = base + j*128;
            float p = q0*b2f(kp[0]) + q1*b2f(kp[1]);
            p += __shfl_xor(p, 1);
            p += __shfl_xor(p, 2);
            p += __shfl_xor(p, 4);
            p += __shfl_xor(p, 8);
            p += __shfl_xor(p, 16);
            sv[j] = p * 0.125f;                 // 1/sqrt(64)
          } else sv[j] = -1e30f;
        }
        float mx = sv[0];
        #pragma unroll
        for (int j = 1; j < 16; ++j) mx = fmaxf(mx, sv[j]);
        float den = 0.f, e[16];
        #pragma unroll
        for (int j = 0; j < 16; ++j){ e[j] = __expf(sv[j]-mx); den += e[j]; }
        float rd = 1.f/den;
        float o0 = 0.f, o1 = 0.f;
        #pragma unroll
        for (int j = 0; j < 16; ++j){
          if (j <= i){
            const unsigned short* vp = base + j*128 + 64;
            o0 += e[j]*b2f(vp[0]);
            o1 += e[j]*b2f(vp[1]);
          }
        }
        os[row][lid*2]   = f2b(o0*rd);
        os[row][lid*2+1] = f2b(o1*rd);
      }
      __syncthreads();
      // ===== A3: Wo K-split partial (full N=256, K=64) =====
      {
        short8 a2[2];
        #pragma unroll
        for (int kc = 0; kc < 2; ++kc)
          a2[kc] = *(const short8*)&os[mrow][kc*32 + kgrp*8];
        #pragma unroll
        for (int u = 0; u < 2; ++u){
          int n_g = (w*2+u)*16 + mrow;
          const unsigned short* wp = wo + (size_t)l*65536 + (size_t)n_g*256 + s*64 + kgrp*8;
          f32x4 acc = {0,0,0,0};
          #pragma unroll
          for (int kc = 0; kc < 2; ++kc){
            short8 b0 = *(const short8*)(wp + kc*32);
            acc = __builtin_amdgcn_mfma_f32_16x16x32_bf16(a2[kc], b0, acc, 0,0,0);
          }
          #pragma unroll
          for (int r = 0; r < 4; ++r)
            zbuf[((size_t)(c*4+s)*16 + kgrp*4 + r)*256 + n_g] = f2b(acc[r]);
        }
      }
      PUBWAIT(0);
      // ===== A4: sum partials + bias + residual -> LN1 + cc + LN2 =====
      {
        int row = w*2 + (lane >> 5), c8 = (lane & 31)*8;
        float t[8];
        #pragma unroll
        for (int k = 0; k < 8; ++k) t[k] = bo_[l*256 + c8 + k] + xf[row][c8+k];
        #pragma unroll
        for (int ss = 0; ss < 4; ++ss){
          const unsigned short* p = zbuf + ((size_t)(c*4+ss)*16 + row)*256 + c8;
          short8 v = *(const short8*)p;
          #pragma unroll
          for (int k = 0; k < 8; ++k) t[k] += b2f(((unsigned short*)&v)[k]);
        }
        float sm = 0, sq = 0;
        #pragma unroll
        for (int k = 0; k < 8; ++k){ sm += t[k]; sq += t[k]*t[k]; }
        sm += __shfl_xor(sm,1);  sq += __shfl_xor(sq,1);
        sm += __shfl_xor(sm,2);  sq += __shfl_xor(sq,2);
        sm += __shfl_xor(sm,4);  sq += __shfl_xor(sq,4);
        sm += __shfl_xor(sm,8);  sq += __shfl_xor(sq,8);
        sm += __shfl_xor(sm,16); sq += __shfl_xor(sq,16);
        float mean = sm*(1.f/256), var = sq*(1.f/256) - mean*mean;
        float rs = rsqrtf(var + EPS_);
        const float* g1p = g1 + l*256 + c8;
        const float* b1p = be1 + l*256 + c8;
        const unsigned short* ccp = cc + ((size_t)l*128 + c*16 + row)*256 + c8;
        #pragma unroll
        for (int k = 0; k < 8; ++k)
          t[k] = (t[k]-mean)*rs*g1p[k] + b1p[k] + b2f(ccp[k]);
        sm = 0; sq = 0;
        #pragma unroll
        for (int k = 0; k < 8; ++k){ sm += t[k]; sq += t[k]*t[k]; }
        sm += __shfl_xor(sm,1);  sq += __shfl_xor(sq,1);
        sm += __shfl_xor(sm,2);  sq += __shfl_xor(sq,2);
        sm += __shfl_xor(sm,4);  sq += __shfl_xor(sq,4);
        sm += __shfl_xor(sm,8);  sq += __shfl_xor(sq,8);
        sm += __shfl_xor(sm,16); sq += __shfl_xor(sq,16);
        mean = sm*(1.f/256); var = sq*(1.f/256) - mean*mean;
        rs = rsqrtf(var + EPS_);
        const float* g2p = g2 + l*256 + c8;
        const float* b2p = be2 + l*256 + c8;
        #pragma unroll
        for (int k = 0; k < 8; ++k){
          float y = (t[k]-mean)*rs*g2p[k] + b2p[k];
          yf[row][c8+k] = y;
          xb[row][c8+k] = f2b(y);
        }
      }
      __syncthreads();
      // ===== B1: lin1 N-slice (s*256 .. +256) + relu -> hs =====
      {
        short8 a[8];
        #pragma unroll
        for (int kc = 0; kc < 8; ++kc)
          a[kc] = *(const short8*)&xb[mrow][kc*32 + kgrp*8];
        const unsigned short* wl = wl1 + (size_t)l*262144;
        #pragma unroll
        for (int u = 0; u < 2; ++u){
          int n_sl = (w*2+u)*16 + mrow;           // 0..255 within slice
          const unsigned short* wp = wl + (size_t)(s*256 + n_sl)*256 + kgrp*8;
          f32x4 acc = {0,0,0,0};
          #pragma unroll
          for (int kc = 0; kc < 8; ++kc){
            short8 b0 = *(const short8*)(wp + kc*32);
            acc = __builtin_amdgcn_mfma_f32_16x16x32_bf16(a[kc], b0, acc, 0,0,0);
          }
          float bias = bl1[l*1024 + s*256 + n_sl];
          #pragma unroll
          for (int r = 0; r < 4; ++r){
            float h = acc[r] + bias;
            hs[kgrp*4 + r][n_sl] = f2b(h > 0.f ? h : 0.f);
          }
        }
      }
      __syncthreads();
      // ===== B2: lin2 K-split partial (full N=256, K=s*256..+256) =====
      {
        short8 ah[8];
        #pragma unroll
        for (int kc = 0; kc < 8; ++kc)
          ah[kc] = *(const short8*)&hs[mrow][kc*32 + kgrp*8];
        #pragma unroll
        for (int u = 0; u < 2; ++u){
          int n_g = (w*2+u)*16 + mrow;
          const unsigned short* wp = wl2 + (size_t)l*262144 + (size_t)n_g*1024 + s*256 + kgrp*8;
          f32x4 acc = {0,0,0,0};
          #pragma unroll
          for (int kc = 0; kc < 8; ++kc){
            short8 b0 = *(const short8*)(wp + kc*32);
            acc = __builtin_amdgcn_mfma_f32_16x16x32_bf16(ah[kc], b0, acc, 0,0,0);
          }
          #pragma unroll
          for (int r = 0; r < 4; ++r)
            z2buf[((size_t)(c*4+s)*16 + kgrp*4 + r)*256 + n_g] = f2b(acc[r]);
        }
      }
      PUBWAIT(1);
      // ===== B3: sum partials + bias + residual -> LN3 (+ head @ l==11) =====
      {
        int row = w*2 + (lane >> 5), c8 = (lane & 31)*8;
        float t[8];
        #pragma unroll
        for (int k = 0; k < 8; ++k) t[k] = bl2[l*256 + c8 + k] + yf[row][c8+k];
        #pragma unroll
        for (int ss = 0; ss < 4; ++ss){
          const unsigned short* p = z2buf + ((size_t)(c*4+ss)*16 + row)*256 + c8;
          short8 v = *(const short8*)p;
          #pragma unroll
          for (int k = 0; k < 8; ++k) t[k] += b2f(((unsigned short*)&v)[k]);
        }
        float sm = 0, sq = 0;
        #pragma unroll
        for (int k = 0; k < 8; ++k){ sm += t[k]; sq += t[k]*t[k]; }
        sm += __shfl_xor(sm,1);  sq += __shfl_xor(sq,1);
        sm += __shfl_xor(sm,2);  sq += __shfl_xor(sq,2);
        sm += __shfl_xor(sm,4);  sq += __shfl_xor(sq,4);
        sm += __shfl_xor(sm,8);  sq += __shfl_xor(sq,8);
        sm += __shfl_xor(sm,16); sq += __shfl_xor(sq,16);
        float mean = sm*(1.f/256), var = sq*(1.f/256) - mean*mean;
        float rs = rsqrtf(var + EPS_);
        const float* g3p = g3 + l*256 + c8;
        const float* b3p = be3 + l*256 + c8;
        float xn[8];
        #pragma unroll
        for (int k = 0; k < 8; ++k)
          xn[k] = (t[k]-mean)*rs*g3p[k] + b3p[k];
        if (l == 11){
          if (s == 0){
            float pr[4];
            #pragma unroll
            for (int p = 0; p < 4; ++p){
              float a = 0.f;
              #pragma unroll
              for (int k = 0; k < 8; ++k) a += xn[k]*outW[p*256 + c8 + k];
              a += __shfl_xor(a,1); a += __shfl_xor(a,2);
              a += __shfl_xor(a,4); a += __shfl_xor(a,8);
              a += __shfl_xor(a,16);
              pr[p] = a;
            }
            if ((lane & 31) == 0){
              int g = c*16 + row;
              #pragma unroll
              for (int p = 0; p < 4; ++p){
                float tt = pr[p] + outb[p];
                float sg = 1.f/(1.f + __expf(-tt));
                out[((size_t)g*16 + i)*4 + p] = plow[p] + (phigh[p]-plow[p])*sg;
              }
            }
          }
          if (i < 15){
            const float* pp = pos + (i+1)*256 + c8;
            #pragma unroll
            for (int k = 0; k < 8; ++k) xn[k] += pp[k];
          }
        }
        #pragma unroll
        for (int k = 0; k < 8; ++k){
          xf[row][c8+k] = xn[k];
          xb[row][c8+k] = f2b(xn[k]);
        }
      }
      __syncthreads();
    }
  }
}

extern "C" void kernel_launch(void* const* d_in, const int* in_sizes, int n_in,
                              void* d_out, int out_size, void* d_ws, size_t ws_size,
                              hipStream_t stream) {
  const float* U_real = (const float*)d_in[0];
  const float* U_imag = (const float*)d_in[1];
  const float* tok_W  = (const float*)d_in[2];
  const float* tok_b  = (const float*)d_in[3];
  const float* pos    = (const float*)d_in[4];
  const float* saW    = (const float*)d_in[5];
  const float* sab    = (const float*)d_in[6];
  const float* saWo   = (const float*)d_in[7];
  const float* sabo   = (const float*)d_in[8];
  const float* caW    = (const float*)d_in[9];
  const float* cab    = (const float*)d_in[10];
  const float* caWo   = (const float*)d_in[11];
  const float* cabo   = (const float*)d_in[12];
  const float* l1W    = (const float*)d_in[13];
  const float* l1b    = (const float*)d_in[14];
  const float* l2W    = (const float*)d_in[15];
  const float* l2b    = (const float*)d_in[16];
  const float* g1     = (const float*)d_in[17];
  const float* be1    = (const float*)d_in[18];
  const float* g2     = (const float*)d_in[19];
  const float* be2    = (const float*)d_in[20];
  const float* g3     = (const float*)d_in[21];
  const float* be3    = (const float*)d_in[22];
  const float* outW   = (const float*)d_in[23];
  const float* outb   = (const float*)d_in[24];
  const float* plow   = (const float*)d_in[25];
  const float* phigh  = (const float*)d_in[26];

  char* ws = (char*)d_ws;
  unsigned short* wb    = (unsigned short*)(ws + OFF_WQKV);
  float* srcb           = (float*)(ws + OFF_SRC);
  unsigned short* ccb   = (unsigned short*)(ws + OFF_CC);
  unsigned short* kvc   = (unsigned short*)(ws + OFF_KV);
  unsigned short* zbuf  = (unsigned short*)(ws + OFF_ZBUFB);
  unsigned short* z2buf = (unsigned short*)(ws + OFF_Z2B16);
  int* flags            = (int*)(ws + OFF_FLAGS);

  (void)hipMemsetAsync(ws + OFF_FLAGS, 0, 512, stream);
  k_conv<<<dim3(4608), dim3(256), 0, stream>>>(saW, saWo, l1W, l2W, wb);
  k_src<<<dim3(128), dim3(256), 0, stream>>>(U_real, U_imag, tok_W, tok_b, srcb);
  k_cc<<<dim3(1536), dim3(256), 0, stream>>>(caW, cab, caWo, cabo, srcb, ccb);
  k_main<<<dim3(32), dim3(512), 0, stream>>>(
      wb,
      (unsigned short*)(ws + OFF_WO),
      (unsigned short*)(ws + OFF_L1),
      (unsigned short*)(ws + OFF_L2),
      sab, sabo, l1b, l2b,
      g1, be1, g2, be2, g3, be3,
      ccb, srcb, pos, outW, outb, plow, phigh,
      kvc, zbuf, z2buf, flags, (float*)d_out);
}